// Round 14
// baseline (234.267 us; speedup 1.0000x reference)
//
#include <hip/hip_runtime.h>

#define N_NODES 100000
#define IN_CH 64
#define HID 128
#define BSH 8                          // 256-node buckets
#define NBUCK ((N_NODES + 255) >> 8)   // 391 buckets
#define NCB 512                        // 512 edge chunks
#define CAPB 4864                      // place staging cap (mean 4092, sd 64 -> +12 sigma)

typedef short short8 __attribute__((ext_vector_type(8)));
typedef float floatx4 __attribute__((ext_vector_type(4)));
typedef float floatx2 __attribute__((ext_vector_type(2)));

__device__ __forceinline__ unsigned short f2bf(float f) {
    unsigned u = __builtin_bit_cast(unsigned, f);
    u += 0x7fffu + ((u >> 16) & 1u);  // RNE
    return (unsigned short)(u >> 16);
}

// ========= fused hist + prep (bf16/fp8 converts of x + weight packs) =========
template <int K>
__device__ __forceinline__ void pack_dev(const float* __restrict__ Wn,
                                         const float* __restrict__ Ws,
                                         unsigned short* __restrict__ Bpack, int idx) {
    int s = idx >> 9;
    int rem = idx & 511;
    int t = rem >> 6;
    int lane = rem & 63;
    int quad = lane >> 4;
    int n = t * 16 + (lane & 15);
    unsigned short v[8];
#pragma unroll
    for (int j = 0; j < 8; ++j) {
        int k = s * 32 + quad * 8 + j;
        float w = (k < K) ? Wn[(size_t)k * HID + n] : Ws[(size_t)(k - K) * HID + n];
        v[j] = f2bf(w);
    }
    *(short8*)(Bpack + (size_t)idx * 8) = *(short8*)v;
}

// blocks [0,NCB): dst histogram; [NCB,NCB+8): pack0; [NCB+8,NCB+24): pack1; rest: x convert
// R28: edge-stream loads vectorized int4; chunk multiple of 4 (host).
__global__ __launch_bounds__(256) void histprep_kernel(const int* __restrict__ dst,
                                                       int* __restrict__ table, int E, int chunk,
                                                       const float* __restrict__ x,
                                                       unsigned short* __restrict__ x_bf,
                                                       unsigned char* __restrict__ x_f8,
                                                       const float* __restrict__ Wn0,
                                                       const float* __restrict__ Ws0,
                                                       unsigned short* __restrict__ Bpack0,
                                                       const float* __restrict__ Wn1,
                                                       const float* __restrict__ Ws1,
                                                       unsigned short* __restrict__ Bpack1,
                                                       int* __restrict__ scan_done, int n4) {
    int b = blockIdx.x;
    if (b < NCB) {
        if (b == 0 && threadIdx.x == 0) *scan_done = 0;  // init for scan12's last-block pattern
        __shared__ int h[NBUCK];
        for (int i = threadIdx.x; i < NBUCK; i += 256) h[i] = 0;
        __syncthreads();
        int e0 = b * chunk;
        int e1 = min(E, e0 + chunk);
        int t = threadIdx.x;
        if (((E | chunk) & 3) == 0) {
            int len4 = (e1 - e0) >> 2;
            const int4* d4 = (const int4*)(dst + e0);
            for (int i = t; i < len4; i += 256) {
                int4 dd = d4[i];
                atomicAdd(&h[dd.x >> BSH], 1);
                atomicAdd(&h[dd.y >> BSH], 1);
                atomicAdd(&h[dd.z >> BSH], 1);
                atomicAdd(&h[dd.w >> BSH], 1);
            }
            for (int e = e0 + (len4 << 2) + t; e < e1; e += 256) atomicAdd(&h[dst[e] >> BSH], 1);
        } else {
            for (int e = e0 + t; e < e1; e += 256) atomicAdd(&h[dst[e] >> BSH], 1);
        }
        __syncthreads();
        for (int i = threadIdx.x; i < NBUCK; i += 256) table[i * NCB + b] = h[i];
    } else if (b < NCB + 8) {
        pack_dev<IN_CH>(Wn0, Ws0, Bpack0, (b - NCB) * 256 + threadIdx.x);
    } else if (b < NCB + 24) {
        pack_dev<HID>(Wn1, Ws1, Bpack1, (b - NCB - 8) * 256 + threadIdx.x);
    } else {
        int i = (b - NCB - 24) * 256 + threadIdx.x;
        if (i < n4) {
            float4 v = ((const float4*)x)[i];
            ushort4 o;
            o.x = f2bf(v.x); o.y = f2bf(v.y); o.z = f2bf(v.z); o.w = f2bf(v.w);
            ((ushort4*)x_bf)[i] = o;
            int p8 = __builtin_amdgcn_cvt_pk_fp8_f32(v.x, v.y, 0, false);
            p8 = __builtin_amdgcn_cvt_pk_fp8_f32(v.z, v.w, p8, true);
            ((unsigned*)x_f8)[i] = (unsigned)p8;
        }
    }
}

// ===== fused scan: per-bucket pair-scan over NCB=512 block counts (2/thread) +
// ===== last-done block scans the NBUCK=391 bucket totals (2/thread).
// R29: P1 results written TRANSPOSED into ttab[block][bucket] so bin's
// latency-exposed LDS-cursor init becomes a coalesced row read (was a 391-load
// stride-2KB column). These strided writes are fire-and-forget into an
// L2-resident 0.8MB buffer — latency hidden. Values integer-identical.
__global__ __launch_bounds__(256) void scan12_kernel(const int* __restrict__ table,
                                                     int* __restrict__ ttab,
                                                     int* __restrict__ tot,
                                                     int* __restrict__ bstart,
                                                     int* __restrict__ ptr,
                                                     int* __restrict__ scan_done, int E) {
    __shared__ int s[256];
    __shared__ int lastflag;
    int b = blockIdx.x, t = threadIdx.x;
    // P1: exclusive scan of this bucket's 512 chunk counts (pairs)
    int c0 = table[b * NCB + 2 * t];
    int c1 = table[b * NCB + 2 * t + 1];
    int s2 = c0 + c1;
    s[t] = s2;
    __syncthreads();
#pragma unroll
    for (int off = 1; off < 256; off <<= 1) {
        int v = (t >= off) ? s[t - off] : 0;
        __syncthreads();
        s[t] += v;
        __syncthreads();
    }
    int excl2 = s[t] - s2;
    ttab[(2 * t) * NBUCK + b] = excl2;            // transposed (R29)
    ttab[(2 * t + 1) * NBUCK + b] = excl2 + c0;   // transposed (R29)
    if (t == 255) {
        __hip_atomic_store(&tot[b], s[255], __ATOMIC_RELAXED, __HIP_MEMORY_SCOPE_AGENT);
        int prev = __hip_atomic_fetch_add(scan_done, 1, __ATOMIC_ACQ_REL, __HIP_MEMORY_SCOPE_AGENT);
        lastflag = (prev == NBUCK - 1);
    }
    __syncthreads();
    if (!lastflag) return;
    // P2: bucket-start scan over NBUCK totals (pairs)
    int v0 = (2 * t < NBUCK)
                 ? __hip_atomic_load(&tot[2 * t], __ATOMIC_RELAXED, __HIP_MEMORY_SCOPE_AGENT) : 0;
    int v1 = (2 * t + 1 < NBUCK)
                 ? __hip_atomic_load(&tot[2 * t + 1], __ATOMIC_RELAXED, __HIP_MEMORY_SCOPE_AGENT) : 0;
    int p2 = v0 + v1;
    __syncthreads();
    s[t] = p2;
    __syncthreads();
#pragma unroll
    for (int off = 1; off < 256; off <<= 1) {
        int u = (t >= off) ? s[t - off] : 0;
        __syncthreads();
        s[t] += u;
        __syncthreads();
    }
    int e2 = s[t] - p2;
    if (2 * t < NBUCK) bstart[2 * t] = e2;
    if (2 * t + 1 < NBUCK) bstart[2 * t + 1] = e2 + v0;
    if (t == 0) {
        bstart[NBUCK] = E;
        ptr[N_NODES] = E;
    }
}

// R28: src/dst loads vectorized int4. R29: cursor init reads the TRANSPOSED
// ttab row (contiguous 391 ints) + bstart (contiguous) — fully coalesced.
__global__ __launch_bounds__(256) void bin_kernel(const int* __restrict__ src,
                                                  const int* __restrict__ dst,
                                                  const int* __restrict__ ttab,
                                                  const int* __restrict__ bstart,
                                                  unsigned* __restrict__ binned, int E, int chunk) {
    __shared__ int cur[NBUCK];
    int blk = blockIdx.x;
    const int* trow = ttab + (size_t)blk * NBUCK;
    for (int i = threadIdx.x; i < NBUCK; i += 256) cur[i] = bstart[i] + trow[i];
    __syncthreads();
    int e0 = blk * chunk;
    int e1 = min(E, e0 + chunk);
    int t = threadIdx.x;
    if (((E | chunk) & 3) == 0) {
        int len4 = (e1 - e0) >> 2;
        const int4* s4 = (const int4*)(src + e0);
        const int4* d4 = (const int4*)(dst + e0);
        for (int i = t; i < len4; i += 256) {
            int4 dd = d4[i];
            int4 ss = s4[i];
            const int dv[4] = {dd.x, dd.y, dd.z, dd.w};
            const int sv[4] = {ss.x, ss.y, ss.z, ss.w};
#pragma unroll
            for (int q = 0; q < 4; ++q) {
                int pos = atomicAdd(&cur[dv[q] >> BSH], 1);  // LDS atomic
                if ((unsigned)pos < (unsigned)E)  // replay guard, no-op on real data
                    binned[pos] = (unsigned)sv[q] | ((unsigned)(dv[q] & 255) << 17);
            }
        }
        for (int e = e0 + (len4 << 2) + t; e < e1; e += 256) {
            int d = dst[e];
            int pos = atomicAdd(&cur[d >> BSH], 1);
            if ((unsigned)pos < (unsigned)E)
                binned[pos] = (unsigned)src[e] | ((unsigned)(d & 255) << 17);
        }
    } else {
        for (int e = e0 + t; e < e1; e += 256) {
            int d = dst[e];
            int pos = atomicAdd(&cur[d >> BSH], 1);
            if ((unsigned)pos < (unsigned)E)
                binned[pos] = (unsigned)src[e] | ((unsigned)(d & 255) << 17);
        }
    }
}

// place: one 256-node bucket per block. R27: LDS-staged scatter + coalesced
// stream-out. R28: binned loads vectorized uint4 with head/body/tail alignment.
// sorted[] content per node segment is the same multiset (arrival-order class,
// absmax-plateau proven stable R16-R28). Fallback if bucket exceeds CAPB
// (never on real data; replay-safe).
__global__ __launch_bounds__(256) void place_kernel(const unsigned* __restrict__ binned,
                                                    const int* __restrict__ bstart,
                                                    int* __restrict__ ptr,
                                                    int* __restrict__ sorted, int N, int E) {
    __shared__ int deg[256];
    __shared__ int cur[256];
    __shared__ int ssum[256];
    __shared__ int stage[CAPB];
    int b = blockIdx.x, t = threadIdx.x;
    int start = bstart[b], end = bstart[b + 1];
    // poison-robust clamps: no-ops on real data (0 <= start <= end <= E)
    start = max(0, min(start, E));
    end = max(start, min(end, E));
    const int cnt = end - start;
    deg[t] = 0;
    __syncthreads();
    // ---- degree count (vectorized: head/body/tail) ----
    {
        int h = min((4 - (start & 3)) & 3, cnt);
        for (int i = start + t; i < start + h; i += 256)
            atomicAdd(&deg[(binned[i] >> 17) & 255], 1);
        int bs = start + h;
        int n4 = (end - bs) >> 2;
        const uint4* b4 = (const uint4*)(binned + bs);
        for (int i = t; i < n4; i += 256) {
            uint4 p = b4[i];
            atomicAdd(&deg[(p.x >> 17) & 255], 1);
            atomicAdd(&deg[(p.y >> 17) & 255], 1);
            atomicAdd(&deg[(p.z >> 17) & 255], 1);
            atomicAdd(&deg[(p.w >> 17) & 255], 1);
        }
        for (int i = bs + (n4 << 2) + t; i < end; i += 256)
            atomicAdd(&deg[(binned[i] >> 17) & 255], 1);
    }
    __syncthreads();
    int a = deg[t];
    ssum[t] = a;
    __syncthreads();
#pragma unroll
    for (int off = 1; off < 256; off <<= 1) {
        int u = (t >= off) ? ssum[t - off] : 0;
        __syncthreads();
        ssum[t] += u;
        __syncthreads();
    }
    int excl = ssum[t] - a;
    int n0 = b * 256 + t;
    if (n0 < N) ptr[n0] = start + excl;
    if (cnt <= CAPB) {
        // ---- staged path: LDS scatter (relative), coalesced global stream ----
        cur[t] = excl;  // region-relative
        __syncthreads();
        int h = min((4 - (start & 3)) & 3, cnt);
        for (int i = start + t; i < start + h; i += 256) {
            unsigned p = binned[i];
            int rel = atomicAdd(&cur[(p >> 17) & 255], 1);
            if ((unsigned)rel < (unsigned)CAPB) stage[rel] = (int)(p & 0x1FFFF);
        }
        int bs = start + h;
        int n4 = (end - bs) >> 2;
        const uint4* b4 = (const uint4*)(binned + bs);
        for (int i = t; i < n4; i += 256) {
            uint4 pk = b4[i];
            const unsigned pv[4] = {pk.x, pk.y, pk.z, pk.w};
#pragma unroll
            for (int q = 0; q < 4; ++q) {
                int rel = atomicAdd(&cur[(pv[q] >> 17) & 255], 1);  // LDS atomic
                if ((unsigned)rel < (unsigned)CAPB) stage[rel] = (int)(pv[q] & 0x1FFFF);
            }
        }
        for (int i = bs + (n4 << 2) + t; i < end; i += 256) {
            unsigned p = binned[i];
            int rel = atomicAdd(&cur[(p >> 17) & 255], 1);
            if ((unsigned)rel < (unsigned)CAPB) stage[rel] = (int)(p & 0x1FFFF);
        }
        __syncthreads();
        for (int i = t; i < cnt; i += 256) sorted[start + i] = stage[i];  // 256B/wave
    } else {
        // ---- fallback (replay/pathological): direct scatter, absolute offsets ----
        cur[t] = excl;
        __syncthreads();
        for (int i = start + t; i < end; i += 256) {
            unsigned p = binned[i];
            int dl = (p >> 17) & 255;
            int pos = start + atomicAdd(&cur[dl], 1);
            if ((unsigned)pos < (unsigned)E) sorted[pos] = (int)(p & 0x1FFFF);
        }
    }
}

// ==== gather + mean, WIDE rows (16B/lane), 2-STAGE feature-load pipeline ====
// Lesson chain: g4 killed VALU overhead (R19); g8 over-queued requests (R20);
// g4p srcs-prefetch won -5.3us (R21); w16 wide rows won -4us (R23); nperm
// degree-sort regressed +15.6us (R24: keep consecutive node order / locality);
// w16p 2-stage pipeline won -3.9us (R25); direct-CSR global atomics regressed
// +149us (R26: returning atomics at random addresses serialize per line).
// BIT-EXACT accumulation tree: partial q = j mod 4, combine (p0+p1)+(p2+p3).
// Clamps keep rocprof replay in-bounds (no-ops on real data: max real deg ~55).
template <int C>
__global__ __launch_bounds__(256) void gather_mean_w16p(const int* __restrict__ ptr,
                                                        const int* __restrict__ srcs,
                                                        const unsigned char* __restrict__ feat,
                                                        unsigned short* __restrict__ mean, int N,
                                                        int E) {
    constexpr int R = C / 16;          // lanes per row (4 for C=64, 8 for C=128)
    constexpr int LOGR = (C == 64) ? 2 : 3;
    constexpr int NPW = 64 / R;        // nodes per wave (16 or 8)
    const int lane = threadIdx.x & 63;
    const int g = lane >> LOGR;        // node slot within wave
    const int l = lane & (R - 1);      // 16B segment within row
    const int w = (blockIdx.x * 4 + (threadIdx.x >> 6)) * NPW + g;  // node id (consecutive)
    if (w >= N) return;
    int s0 = ptr[w], s1 = ptr[w + 1];
    s0 = max(0, min(s0, E));
    s1 = max(s0, min(s1, E));
    const int deg = min(s1 - s0, 4096);

    floatx2 accq[4][8];  // 4 partials x 16 channels
#pragma unroll
    for (int q = 0; q < 4; ++q)
#pragma unroll
        for (int u = 0; u < 8; ++u) { accq[q][u][0] = 0.0f; accq[q][u][1] = 0.0f; }

    const int nfull = deg & ~3;
    int j = 0;
    if (nfull > 0) {
        // ---- pipeline prologue: block0 rows + block1 indices in flight ----
        int cidn[4];  // indices of block j+1 (clamped reload of block 0 at the end)
        uint4 v[4];   // rows of block j
        {
            int cid0[4];
#pragma unroll
            for (int q = 0; q < 4; ++q)
                cid0[q] = (int)min((unsigned)srcs[s0 + q], (unsigned)(N_NODES - 1));
#pragma unroll
            for (int q = 0; q < 4; ++q)
                v[q] = *(const uint4*)(feat + (size_t)cid0[q] * C + l * 16);
            int base1 = (4 < nfull) ? s0 + 4 : s0;
#pragma unroll
            for (int q = 0; q < 4; ++q)
                cidn[q] = (int)min((unsigned)srcs[base1 + q], (unsigned)(N_NODES - 1));
        }
        for (; j < nfull; j += 4) {
            // issue block j+1's rows into the spare buffer (last iter: harmless reload)
            uint4 vn[4];
#pragma unroll
            for (int q = 0; q < 4; ++q)
                vn[q] = *(const uint4*)(feat + (size_t)cidn[q] * C + l * 16);
            // issue block j+2's indices (branchless clamp to s0; result unused at end)
            int base2 = (j + 8 < nfull) ? s0 + j + 8 : s0;
            int cid2[4];
#pragma unroll
            for (int q = 0; q < 4; ++q)
                cid2[q] = (int)min((unsigned)srcs[base2 + q], (unsigned)(N_NODES - 1));
            // accumulate block j (VALU hides under the loads above):
            // edge j+q -> partial q (ascending within partial)
#pragma unroll
            for (int q = 0; q < 4; ++q) {
                const uint dw[4] = {v[q].x, v[q].y, v[q].z, v[q].w};
#pragma unroll
                for (int d = 0; d < 4; ++d) {
                    accq[q][2 * d + 0] += __builtin_amdgcn_cvt_pk_f32_fp8(dw[d], false);
                    accq[q][2 * d + 1] += __builtin_amdgcn_cvt_pk_f32_fp8(dw[d], true);
                }
            }
#pragma unroll
            for (int q = 0; q < 4; ++q) { v[q] = vn[q]; cidn[q] = cid2[q]; }
        }
    }
    if (j < deg) {  // one branchless masked block for the 1..3 remaining edges
        int cid[4];
#pragma unroll
        for (int q = 0; q < 4; ++q) {
            int jj = min(j + q, deg - 1);
            cid[q] = (int)min((unsigned)srcs[s0 + jj], (unsigned)(N_NODES - 1));
        }
        uint4 v[4];
#pragma unroll
        for (int q = 0; q < 4; ++q)
            v[q] = *(const uint4*)(feat + (size_t)cid[q] * C + l * 16);
#pragma unroll
        for (int q = 0; q < 4; ++q) {
            uint dw[4] = {v[q].x, v[q].y, v[q].z, v[q].w};
#pragma unroll
            for (int d = 0; d < 4; ++d) dw[d] = (j + q < deg) ? dw[d] : 0u;  // +0.0 exact
#pragma unroll
            for (int d = 0; d < 4; ++d) {
                accq[q][2 * d + 0] += __builtin_amdgcn_cvt_pk_f32_fp8(dw[d], false);
                accq[q][2 * d + 1] += __builtin_amdgcn_cvt_pk_f32_fp8(dw[d], true);
            }
        }
    }
    // combine partials in the old tree order: (p0+p1)+(p2+p3)
#pragma unroll
    for (int u = 0; u < 8; ++u) {
        accq[0][u] += accq[1][u];
        accq[2][u] += accq[3][u];
        accq[0][u] += accq[2][u];
    }
    const float inv = (deg > 0) ? 1.0f / (float)deg : 0.0f;
    unsigned short o[16];
#pragma unroll
    for (int u = 0; u < 8; ++u) {
        o[2 * u + 0] = f2bf(accq[0][u][0] * inv);
        o[2 * u + 1] = f2bf(accq[0][u][1] * inv);
    }
    unsigned short* mp = mean + (size_t)w * C + l * 16;  // 16 channels per lane
    *(uint4*)(mp + 0) = ((const uint4*)o)[0];
    *(uint4*)(mp + 8) = ((const uint4*)o)[1];
}

// ================= MFMA SAGE GEMM: relu([mean|h] @ [Wn;Ws] + b) =================
// Self (h) half stays bf16 — R15 PMC lesson: fp8 on the un-averaged self path
// quadruples absmax (0.031->0.117, fails). fp8 only where a mean follows.
// !FUSE_FC: outputs staged through LDS and stored as full coalesced lines
// (direct per-lane 1-2B stores caused 2.5x HBM write amplification — R13 PMC).
// Poison-robust by construction: control flow depends only on N and blockIdx.
template <int KT, bool FUSE_FC>
__global__ __launch_bounds__(256) void sage_gemm_mfma(const unsigned short* __restrict__ meanb,
                                                      const unsigned short* __restrict__ hb,
                                                      const unsigned short* __restrict__ Bpack,
                                                      const float* __restrict__ bias,
                                                      const float* __restrict__ fcw,
                                                      const float* __restrict__ fcb,
                                                      unsigned short* __restrict__ outb,
                                                      unsigned char* __restrict__ out8,
                                                      float* __restrict__ outf, int N) {
    constexpr int KH = KT / 2;
    constexpr int LDA = KT + 8;
    __shared__ unsigned short As[64 * LDA];
    const int t = threadIdx.x;
    const int row0 = blockIdx.x * 64;

    constexpr int SEGS = KT / 8;
    for (int c = t; c < 64 * SEGS; c += 256) {
        int r = c / SEGS, seg = c % SEGS;
        int rsrc = row0 + r;
        if (rsrc >= N) rsrc = N - 1;
        const unsigned short* srcp = (seg < SEGS / 2)
                                         ? meanb + (size_t)rsrc * KH + seg * 8
                                         : hb + (size_t)rsrc * KH + (seg - SEGS / 2) * 8;
        *(uint4*)&As[r * LDA + seg * 8] = *(const uint4*)srcp;
    }
    __syncthreads();

    const int lane = t & 63;
    const int wave = t >> 6;
    const int quad = lane >> 4;
    const int lo = lane & 15;

    floatx4 acc[8];
#pragma unroll
    for (int i = 0; i < 8; ++i)
#pragma unroll
        for (int r = 0; r < 4; ++r) acc[i][r] = 0.0f;

    const unsigned short* abase = &As[(wave * 16 + lo) * LDA + quad * 8];
#pragma unroll
    for (int s = 0; s < KT / 32; ++s) {
        short8 a = *(const short8*)(abase + s * 32);
        const short8* bp = (const short8*)Bpack + (size_t)(s * 8) * 64 + lane;
#pragma unroll
        for (int tt = 0; tt < 8; ++tt) {
            short8 b = bp[tt * 64];
            acc[tt] = __builtin_amdgcn_mfma_f32_16x16x32_bf16(a, b, acc[tt], 0, 0, 0);
        }
    }

    if (!FUSE_FC) {
        // ---- phase A: stage bf16 rows in LDS, stream out full 256B lines ----
        __syncthreads();  // all As (A-tile) reads complete before reuse
#pragma unroll
        for (int tt = 0; tt < 8; ++tt) {
            int col = tt * 16 + lo;
            float bv = bias[col];
#pragma unroll
            for (int r = 0; r < 4; ++r) {
                int rl = wave * 16 + quad * 4 + r;
                As[rl * LDA + col] = f2bf(fmaxf(acc[tt][r] + bv, 0.0f));
            }
        }
        __syncthreads();
        for (int i = t; i < 64 * (HID / 8); i += 256) {  // 16 threads/row, uint4 each
            int r = i >> 4, ch = i & 15;
            int row = row0 + r;
            if (row < N)
                *(uint4*)(outb + (size_t)row * HID + ch * 8) = *(const uint4*)&As[r * LDA + ch * 8];
        }
        // ---- phase B: recompute from live acc, stage fp8 rows, stream 128B lines ----
        __syncthreads();
        unsigned char* As8 = (unsigned char*)As;
#pragma unroll
        for (int tt = 0; tt < 8; ++tt) {
            int col = tt * 16 + lo;
            float bv = bias[col];
#pragma unroll
            for (int r = 0; r < 4; ++r) {
                int rl = wave * 16 + quad * 4 + r;
                float v = fmaxf(acc[tt][r] + bv, 0.0f);
                int p8 = __builtin_amdgcn_cvt_pk_fp8_f32(v, v, 0, false);
                As8[rl * (LDA * 2) + col] = (unsigned char)(p8 & 0xff);
            }
        }
        __syncthreads();
        for (int i = t; i < 64 * (HID / 16); i += 256) {  // 8 threads/row, uint4 each
            int r = i >> 3, ch = i & 7;
            int row = row0 + r;
            if (row < N)
                *(uint4*)(out8 + (size_t)row * HID + ch * 16) =
                    *(const uint4*)&As8[r * (LDA * 2) + ch * 16];
        }
    } else {
        float o0[4] = {}, o1[4] = {};
#pragma unroll
        for (int tt = 0; tt < 8; ++tt) {
            int col = tt * 16 + lo;
            float bv = bias[col];
            float w0 = fcw[col * 2 + 0];
            float w1 = fcw[col * 2 + 1];
#pragma unroll
            for (int r = 0; r < 4; ++r) {
                float v = fmaxf(acc[tt][r] + bv, 0.0f);
                o0[r] += v * w0;
                o1[r] += v * w1;
            }
        }
#pragma unroll
        for (int r = 0; r < 4; ++r) {
#pragma unroll
            for (int m = 8; m >= 1; m >>= 1) {
                o0[r] += __shfl_xor(o0[r], m, 16);
                o1[r] += __shfl_xor(o1[r], m, 16);
            }
        }
        if (lo == 0) {
#pragma unroll
            for (int r = 0; r < 4; ++r) {
                int row = row0 + wave * 16 + quad * 4 + r;
                if (row < N) {
                    outf[(size_t)row * 2 + 0] = o0[r] + fcb[0];
                    outf[(size_t)row * 2 + 1] = o1[r] + fcb[1];
                }
            }
        }
    }
}

extern "C" void kernel_launch(void* const* d_in, const int* in_sizes, int n_in,
                              void* d_out, int out_size, void* d_ws, size_t ws_size,
                              hipStream_t stream) {
    const float* x   = (const float*)d_in[0];
    const int*   ei  = (const int*)d_in[1];
    const float* Wn0 = (const float*)d_in[2];
    const float* Ws0 = (const float*)d_in[3];
    const float* b0  = (const float*)d_in[4];
    const float* Wn1 = (const float*)d_in[5];
    const float* Ws1 = (const float*)d_in[6];
    const float* b1  = (const float*)d_in[7];
    const float* fcw = (const float*)d_in[8];
    const float* fcb = (const float*)d_in[9];
    float* out = (float*)d_out;

    const int E = in_sizes[1] / 2;
    const int* src = ei;
    const int* dst = ei + E;
    const int N = N_NODES;
    const int chunk = (((E + NCB - 1) / NCB) + 3) & ~3;  // multiple of 4 for int4 paths

    // workspace layout
    char* ws = (char*)d_ws;
    size_t off = 0;
    int* table  = (int*)(ws + off); off += (size_t)NBUCK * NCB * 4;
    int* ttab   = (int*)(ws + off); off += (size_t)NCB * NBUCK * 4;  // transposed scan output
    int* tot    = (int*)(ws + off); off += 4096;
    int* bstart = (int*)(ws + off); off += 4096;
    int* scan_done = (int*)(ws + off); off += 256;
    int* ptr    = (int*)(ws + off); off += (size_t)(N + 1) * 4 + 60; off &= ~(size_t)63;
    unsigned* binned = (unsigned*)(ws + off); off += (size_t)E * 4;
    int* sorted = (int*)(ws + off); off += (size_t)E * 4;
    off = (off + 255) & ~(size_t)255;
    unsigned short* x_bf   = (unsigned short*)(ws + off); off += (size_t)N * IN_CH * 2;
    unsigned short* mean0  = (unsigned short*)(ws + off); off += (size_t)N * IN_CH * 2;
    unsigned short* h1_bf  = (unsigned short*)(ws + off); off += (size_t)N * HID * 2;
    unsigned short* mean1  = (unsigned short*)(ws + off); off += (size_t)N * HID * 2;
    unsigned char*  h1_f8  = (unsigned char*)(ws + off);  off += (size_t)N * HID;
    unsigned char*  x_f8   = (unsigned char*)(ws + off);  off += (size_t)N * IN_CH;
    off = (off + 255) & ~(size_t)255;
    unsigned short* Bpack0 = (unsigned short*)(ws + off); off += (size_t)(2 * IN_CH / 32) * 8 * 64 * 8 * 2;
    unsigned short* Bpack1 = (unsigned short*)(ws + off); off += (size_t)(2 * HID / 32) * 8 * 64 * 8 * 2;

    // ---- CSR build + prep ----
    {
        int n4 = N * IN_CH / 4;
        int nblk = NCB + 24 + (n4 + 255) / 256;
        histprep_kernel<<<nblk, 256, 0, stream>>>(dst, table, E, chunk, x, x_bf, x_f8,
                                                  Wn0, Ws0, Bpack0, Wn1, Ws1, Bpack1,
                                                  scan_done, n4);
    }
    scan12_kernel<<<NBUCK, 256, 0, stream>>>(table, ttab, tot, bstart, ptr, scan_done, E);
    bin_kernel<<<NCB, 256, 0, stream>>>(src, dst, ttab, bstart, binned, E, chunk);
    place_kernel<<<NBUCK, 256, 0, stream>>>(binned, bstart, ptr, sorted, N, E);

    // ---- layer 0 (fp8 aggregation, bf16 self): 64 nodes/block (R=4) ----
    gather_mean_w16p<IN_CH><<<(N + 63) / 64, 256, 0, stream>>>(ptr, sorted, x_f8, mean0, N, E);
    sage_gemm_mfma<2 * IN_CH, false><<<(N + 63) / 64, 256, 0, stream>>>(
        mean0, x_bf, Bpack0, b0, nullptr, nullptr, h1_bf, h1_f8, nullptr, N);

    // ---- layer 1 (fp8 aggregation, bf16 self) + fused fc: 32 nodes/block (R=8) ----
    gather_mean_w16p<HID><<<(N + 31) / 32, 256, 0, stream>>>(ptr, sorted, h1_f8, mean1, N, E);
    sage_gemm_mfma<2 * HID, true><<<(N + 63) / 64, 256, 0, stream>>>(
        mean1, h1_bf, Bpack1, b1, fcw, fcb, nullptr, nullptr, out, N);
}

// Round 15
// 225.897 us; speedup vs baseline: 1.0371x; 1.0371x over previous
//
#include <hip/hip_runtime.h>

#define N_NODES 100000
#define IN_CH 64
#define HID 128
#define BSH 8                          // 256-node buckets
#define NBUCK ((N_NODES + 255) >> 8)   // 391 buckets
#define NCB 512                        // 512 edge chunks
#define CAPB 4864                      // place staging cap (mean 4092, sd 64 -> +12 sigma)

typedef short short8 __attribute__((ext_vector_type(8)));
typedef float floatx4 __attribute__((ext_vector_type(4)));
typedef float floatx2 __attribute__((ext_vector_type(2)));

__device__ __forceinline__ unsigned short f2bf(float f) {
    unsigned u = __builtin_bit_cast(unsigned, f);
    u += 0x7fffu + ((u >> 16) & 1u);  // RNE
    return (unsigned short)(u >> 16);
}

// ========= fused hist + prep (bf16/fp8 converts of x + weight packs) =========
template <int K>
__device__ __forceinline__ void pack_dev(const float* __restrict__ Wn,
                                         const float* __restrict__ Ws,
                                         unsigned short* __restrict__ Bpack, int idx) {
    int s = idx >> 9;
    int rem = idx & 511;
    int t = rem >> 6;
    int lane = rem & 63;
    int quad = lane >> 4;
    int n = t * 16 + (lane & 15);
    unsigned short v[8];
#pragma unroll
    for (int j = 0; j < 8; ++j) {
        int k = s * 32 + quad * 8 + j;
        float w = (k < K) ? Wn[(size_t)k * HID + n] : Ws[(size_t)(k - K) * HID + n];
        v[j] = f2bf(w);
    }
    *(short8*)(Bpack + (size_t)idx * 8) = *(short8*)v;
}

// blocks [0,NCB): dst histogram; [NCB,NCB+8): pack0; [NCB+8,NCB+24): pack1; rest: x convert
// R28: edge-stream loads vectorized int4; chunk multiple of 4 (host).
__global__ __launch_bounds__(256) void histprep_kernel(const int* __restrict__ dst,
                                                       int* __restrict__ table, int E, int chunk,
                                                       const float* __restrict__ x,
                                                       unsigned short* __restrict__ x_bf,
                                                       unsigned char* __restrict__ x_f8,
                                                       const float* __restrict__ Wn0,
                                                       const float* __restrict__ Ws0,
                                                       unsigned short* __restrict__ Bpack0,
                                                       const float* __restrict__ Wn1,
                                                       const float* __restrict__ Ws1,
                                                       unsigned short* __restrict__ Bpack1,
                                                       int* __restrict__ scan_done, int n4) {
    int b = blockIdx.x;
    if (b < NCB) {
        if (b == 0 && threadIdx.x == 0) *scan_done = 0;  // init for scan12's last-block pattern
        __shared__ int h[NBUCK];
        for (int i = threadIdx.x; i < NBUCK; i += 256) h[i] = 0;
        __syncthreads();
        int e0 = b * chunk;
        int e1 = min(E, e0 + chunk);
        int t = threadIdx.x;
        if (((E | chunk) & 3) == 0) {
            int len4 = (e1 - e0) >> 2;
            const int4* d4 = (const int4*)(dst + e0);
            for (int i = t; i < len4; i += 256) {
                int4 dd = d4[i];
                atomicAdd(&h[dd.x >> BSH], 1);
                atomicAdd(&h[dd.y >> BSH], 1);
                atomicAdd(&h[dd.z >> BSH], 1);
                atomicAdd(&h[dd.w >> BSH], 1);
            }
            for (int e = e0 + (len4 << 2) + t; e < e1; e += 256) atomicAdd(&h[dst[e] >> BSH], 1);
        } else {
            for (int e = e0 + t; e < e1; e += 256) atomicAdd(&h[dst[e] >> BSH], 1);
        }
        __syncthreads();
        for (int i = threadIdx.x; i < NBUCK; i += 256) table[i * NCB + b] = h[i];
    } else if (b < NCB + 8) {
        pack_dev<IN_CH>(Wn0, Ws0, Bpack0, (b - NCB) * 256 + threadIdx.x);
    } else if (b < NCB + 24) {
        pack_dev<HID>(Wn1, Ws1, Bpack1, (b - NCB - 8) * 256 + threadIdx.x);
    } else {
        int i = (b - NCB - 24) * 256 + threadIdx.x;
        if (i < n4) {
            float4 v = ((const float4*)x)[i];
            ushort4 o;
            o.x = f2bf(v.x); o.y = f2bf(v.y); o.z = f2bf(v.z); o.w = f2bf(v.w);
            ((ushort4*)x_bf)[i] = o;
            int p8 = __builtin_amdgcn_cvt_pk_fp8_f32(v.x, v.y, 0, false);
            p8 = __builtin_amdgcn_cvt_pk_fp8_f32(v.z, v.w, p8, true);
            ((unsigned*)x_f8)[i] = (unsigned)p8;
        }
    }
}

// ===== fused scan: per-bucket pair-scan over NCB=512 block counts (2/thread) +
// ===== last-done block scans the NBUCK=391 bucket totals (2/thread).
// R30 lesson: transposed-table variant (R29) regressed +7.6us — scattered
// strided stores across a 0.8MB span cost more than bin's (TLP-hidden) column
// read. Keep the row-major table.
__global__ __launch_bounds__(256) void scan12_kernel(int* __restrict__ table,
                                                     int* __restrict__ tot,
                                                     int* __restrict__ bstart,
                                                     int* __restrict__ ptr,
                                                     int* __restrict__ scan_done, int E) {
    __shared__ int s[256];
    __shared__ int lastflag;
    int b = blockIdx.x, t = threadIdx.x;
    // P1: exclusive scan of this bucket's 512 chunk counts (pairs)
    int c0 = table[b * NCB + 2 * t];
    int c1 = table[b * NCB + 2 * t + 1];
    int s2 = c0 + c1;
    s[t] = s2;
    __syncthreads();
#pragma unroll
    for (int off = 1; off < 256; off <<= 1) {
        int v = (t >= off) ? s[t - off] : 0;
        __syncthreads();
        s[t] += v;
        __syncthreads();
    }
    int excl2 = s[t] - s2;
    table[b * NCB + 2 * t] = excl2;
    table[b * NCB + 2 * t + 1] = excl2 + c0;
    if (t == 255) {
        __hip_atomic_store(&tot[b], s[255], __ATOMIC_RELAXED, __HIP_MEMORY_SCOPE_AGENT);
        int prev = __hip_atomic_fetch_add(scan_done, 1, __ATOMIC_ACQ_REL, __HIP_MEMORY_SCOPE_AGENT);
        lastflag = (prev == NBUCK - 1);
    }
    __syncthreads();
    if (!lastflag) return;
    // P2: bucket-start scan over NBUCK totals (pairs)
    int v0 = (2 * t < NBUCK)
                 ? __hip_atomic_load(&tot[2 * t], __ATOMIC_RELAXED, __HIP_MEMORY_SCOPE_AGENT) : 0;
    int v1 = (2 * t + 1 < NBUCK)
                 ? __hip_atomic_load(&tot[2 * t + 1], __ATOMIC_RELAXED, __HIP_MEMORY_SCOPE_AGENT) : 0;
    int p2 = v0 + v1;
    __syncthreads();
    s[t] = p2;
    __syncthreads();
#pragma unroll
    for (int off = 1; off < 256; off <<= 1) {
        int u = (t >= off) ? s[t - off] : 0;
        __syncthreads();
        s[t] += u;
        __syncthreads();
    }
    int e2 = s[t] - p2;
    if (2 * t < NBUCK) bstart[2 * t] = e2;
    if (2 * t + 1 < NBUCK) bstart[2 * t + 1] = e2 + v0;
    if (t == 0) {
        bstart[NBUCK] = E;
        ptr[N_NODES] = E;
    }
}

// R28: src/dst loads vectorized int4 (chunk%4==0, E%4==0 -> 16B-aligned bases).
__global__ __launch_bounds__(256) void bin_kernel(const int* __restrict__ src,
                                                  const int* __restrict__ dst,
                                                  const int* __restrict__ table,
                                                  const int* __restrict__ bstart,
                                                  unsigned* __restrict__ binned, int E, int chunk) {
    __shared__ int cur[NBUCK];
    int blk = blockIdx.x;
    for (int i = threadIdx.x; i < NBUCK; i += 256) cur[i] = bstart[i] + table[i * NCB + blk];
    __syncthreads();
    int e0 = blk * chunk;
    int e1 = min(E, e0 + chunk);
    int t = threadIdx.x;
    if (((E | chunk) & 3) == 0) {
        int len4 = (e1 - e0) >> 2;
        const int4* s4 = (const int4*)(src + e0);
        const int4* d4 = (const int4*)(dst + e0);
        for (int i = t; i < len4; i += 256) {
            int4 dd = d4[i];
            int4 ss = s4[i];
            const int dv[4] = {dd.x, dd.y, dd.z, dd.w};
            const int sv[4] = {ss.x, ss.y, ss.z, ss.w};
#pragma unroll
            for (int q = 0; q < 4; ++q) {
                int pos = atomicAdd(&cur[dv[q] >> BSH], 1);  // LDS atomic
                if ((unsigned)pos < (unsigned)E)  // replay guard, no-op on real data
                    binned[pos] = (unsigned)sv[q] | ((unsigned)(dv[q] & 255) << 17);
            }
        }
        for (int e = e0 + (len4 << 2) + t; e < e1; e += 256) {
            int d = dst[e];
            int pos = atomicAdd(&cur[d >> BSH], 1);
            if ((unsigned)pos < (unsigned)E)
                binned[pos] = (unsigned)src[e] | ((unsigned)(d & 255) << 17);
        }
    } else {
        for (int e = e0 + t; e < e1; e += 256) {
            int d = dst[e];
            int pos = atomicAdd(&cur[d >> BSH], 1);
            if ((unsigned)pos < (unsigned)E)
                binned[pos] = (unsigned)src[e] | ((unsigned)(d & 255) << 17);
        }
    }
}

// place: one 256-node bucket per block. R27: LDS-staged scatter + coalesced
// stream-out. R28: binned loads vectorized uint4 with head/body/tail alignment.
// sorted[] content per node segment is the same multiset (arrival-order class,
// absmax-plateau proven stable R16-R28). Fallback if bucket exceeds CAPB
// (never on real data; replay-safe).
__global__ __launch_bounds__(256) void place_kernel(const unsigned* __restrict__ binned,
                                                    const int* __restrict__ bstart,
                                                    int* __restrict__ ptr,
                                                    int* __restrict__ sorted, int N, int E) {
    __shared__ int deg[256];
    __shared__ int cur[256];
    __shared__ int ssum[256];
    __shared__ int stage[CAPB];
    int b = blockIdx.x, t = threadIdx.x;
    int start = bstart[b], end = bstart[b + 1];
    // poison-robust clamps: no-ops on real data (0 <= start <= end <= E)
    start = max(0, min(start, E));
    end = max(start, min(end, E));
    const int cnt = end - start;
    deg[t] = 0;
    __syncthreads();
    // ---- degree count (vectorized: head/body/tail) ----
    {
        int h = min((4 - (start & 3)) & 3, cnt);
        for (int i = start + t; i < start + h; i += 256)
            atomicAdd(&deg[(binned[i] >> 17) & 255], 1);
        int bs = start + h;
        int n4 = (end - bs) >> 2;
        const uint4* b4 = (const uint4*)(binned + bs);
        for (int i = t; i < n4; i += 256) {
            uint4 p = b4[i];
            atomicAdd(&deg[(p.x >> 17) & 255], 1);
            atomicAdd(&deg[(p.y >> 17) & 255], 1);
            atomicAdd(&deg[(p.z >> 17) & 255], 1);
            atomicAdd(&deg[(p.w >> 17) & 255], 1);
        }
        for (int i = bs + (n4 << 2) + t; i < end; i += 256)
            atomicAdd(&deg[(binned[i] >> 17) & 255], 1);
    }
    __syncthreads();
    int a = deg[t];
    ssum[t] = a;
    __syncthreads();
#pragma unroll
    for (int off = 1; off < 256; off <<= 1) {
        int u = (t >= off) ? ssum[t - off] : 0;
        __syncthreads();
        ssum[t] += u;
        __syncthreads();
    }
    int excl = ssum[t] - a;
    int n0 = b * 256 + t;
    if (n0 < N) ptr[n0] = start + excl;
    if (cnt <= CAPB) {
        // ---- staged path: LDS scatter (relative), coalesced global stream ----
        cur[t] = excl;  // region-relative
        __syncthreads();
        int h = min((4 - (start & 3)) & 3, cnt);
        for (int i = start + t; i < start + h; i += 256) {
            unsigned p = binned[i];
            int rel = atomicAdd(&cur[(p >> 17) & 255], 1);
            if ((unsigned)rel < (unsigned)CAPB) stage[rel] = (int)(p & 0x1FFFF);
        }
        int bs = start + h;
        int n4 = (end - bs) >> 2;
        const uint4* b4 = (const uint4*)(binned + bs);
        for (int i = t; i < n4; i += 256) {
            uint4 pk = b4[i];
            const unsigned pv[4] = {pk.x, pk.y, pk.z, pk.w};
#pragma unroll
            for (int q = 0; q < 4; ++q) {
                int rel = atomicAdd(&cur[(pv[q] >> 17) & 255], 1);  // LDS atomic
                if ((unsigned)rel < (unsigned)CAPB) stage[rel] = (int)(pv[q] & 0x1FFFF);
            }
        }
        for (int i = bs + (n4 << 2) + t; i < end; i += 256) {
            unsigned p = binned[i];
            int rel = atomicAdd(&cur[(p >> 17) & 255], 1);
            if ((unsigned)rel < (unsigned)CAPB) stage[rel] = (int)(p & 0x1FFFF);
        }
        __syncthreads();
        for (int i = t; i < cnt; i += 256) sorted[start + i] = stage[i];  // 256B/wave
    } else {
        // ---- fallback (replay/pathological): direct scatter, absolute offsets ----
        cur[t] = excl;
        __syncthreads();
        for (int i = start + t; i < end; i += 256) {
            unsigned p = binned[i];
            int dl = (p >> 17) & 255;
            int pos = start + atomicAdd(&cur[dl], 1);
            if ((unsigned)pos < (unsigned)E) sorted[pos] = (int)(p & 0x1FFFF);
        }
    }
}

// ==== gather + mean, WIDE rows (16B/lane), 2-STAGE feature-load pipeline ====
// Lesson chain: g4 killed VALU overhead (R19); g8 over-queued requests (R20);
// g4p srcs-prefetch won -5.3us (R21); w16 wide rows won -4us (R23); nperm
// degree-sort regressed +15.6us (R24: keep consecutive node order / locality);
// w16p 2-stage pipeline won -3.9us (R25); direct-CSR global atomics regressed
// +149us (R26: returning atomics at random addresses serialize per line).
// BIT-EXACT accumulation tree: partial q = j mod 4, combine (p0+p1)+(p2+p3).
// Clamps keep rocprof replay in-bounds (no-ops on real data: max real deg ~55).
template <int C>
__global__ __launch_bounds__(256) void gather_mean_w16p(const int* __restrict__ ptr,
                                                        const int* __restrict__ srcs,
                                                        const unsigned char* __restrict__ feat,
                                                        unsigned short* __restrict__ mean, int N,
                                                        int E) {
    constexpr int R = C / 16;          // lanes per row (4 for C=64, 8 for C=128)
    constexpr int LOGR = (C == 64) ? 2 : 3;
    constexpr int NPW = 64 / R;        // nodes per wave (16 or 8)
    const int lane = threadIdx.x & 63;
    const int g = lane >> LOGR;        // node slot within wave
    const int l = lane & (R - 1);      // 16B segment within row
    const int w = (blockIdx.x * 4 + (threadIdx.x >> 6)) * NPW + g;  // node id (consecutive)
    if (w >= N) return;
    int s0 = ptr[w], s1 = ptr[w + 1];
    s0 = max(0, min(s0, E));
    s1 = max(s0, min(s1, E));
    const int deg = min(s1 - s0, 4096);

    floatx2 accq[4][8];  // 4 partials x 16 channels
#pragma unroll
    for (int q = 0; q < 4; ++q)
#pragma unroll
        for (int u = 0; u < 8; ++u) { accq[q][u][0] = 0.0f; accq[q][u][1] = 0.0f; }

    const int nfull = deg & ~3;
    int j = 0;
    if (nfull > 0) {
        // ---- pipeline prologue: block0 rows + block1 indices in flight ----
        int cidn[4];  // indices of block j+1 (clamped reload of block 0 at the end)
        uint4 v[4];   // rows of block j
        {
            int cid0[4];
#pragma unroll
            for (int q = 0; q < 4; ++q)
                cid0[q] = (int)min((unsigned)srcs[s0 + q], (unsigned)(N_NODES - 1));
#pragma unroll
            for (int q = 0; q < 4; ++q)
                v[q] = *(const uint4*)(feat + (size_t)cid0[q] * C + l * 16);
            int base1 = (4 < nfull) ? s0 + 4 : s0;
#pragma unroll
            for (int q = 0; q < 4; ++q)
                cidn[q] = (int)min((unsigned)srcs[base1 + q], (unsigned)(N_NODES - 1));
        }
        for (; j < nfull; j += 4) {
            // issue block j+1's rows into the spare buffer (last iter: harmless reload)
            uint4 vn[4];
#pragma unroll
            for (int q = 0; q < 4; ++q)
                vn[q] = *(const uint4*)(feat + (size_t)cidn[q] * C + l * 16);
            // issue block j+2's indices (branchless clamp to s0; result unused at end)
            int base2 = (j + 8 < nfull) ? s0 + j + 8 : s0;
            int cid2[4];
#pragma unroll
            for (int q = 0; q < 4; ++q)
                cid2[q] = (int)min((unsigned)srcs[base2 + q], (unsigned)(N_NODES - 1));
            // accumulate block j (VALU hides under the loads above):
            // edge j+q -> partial q (ascending within partial)
#pragma unroll
            for (int q = 0; q < 4; ++q) {
                const uint dw[4] = {v[q].x, v[q].y, v[q].z, v[q].w};
#pragma unroll
                for (int d = 0; d < 4; ++d) {
                    accq[q][2 * d + 0] += __builtin_amdgcn_cvt_pk_f32_fp8(dw[d], false);
                    accq[q][2 * d + 1] += __builtin_amdgcn_cvt_pk_f32_fp8(dw[d], true);
                }
            }
#pragma unroll
            for (int q = 0; q < 4; ++q) { v[q] = vn[q]; cidn[q] = cid2[q]; }
        }
    }
    if (j < deg) {  // one branchless masked block for the 1..3 remaining edges
        int cid[4];
#pragma unroll
        for (int q = 0; q < 4; ++q) {
            int jj = min(j + q, deg - 1);
            cid[q] = (int)min((unsigned)srcs[s0 + jj], (unsigned)(N_NODES - 1));
        }
        uint4 v[4];
#pragma unroll
        for (int q = 0; q < 4; ++q)
            v[q] = *(const uint4*)(feat + (size_t)cid[q] * C + l * 16);
#pragma unroll
        for (int q = 0; q < 4; ++q) {
            uint dw[4] = {v[q].x, v[q].y, v[q].z, v[q].w};
#pragma unroll
            for (int d = 0; d < 4; ++d) dw[d] = (j + q < deg) ? dw[d] : 0u;  // +0.0 exact
#pragma unroll
            for (int d = 0; d < 4; ++d) {
                accq[q][2 * d + 0] += __builtin_amdgcn_cvt_pk_f32_fp8(dw[d], false);
                accq[q][2 * d + 1] += __builtin_amdgcn_cvt_pk_f32_fp8(dw[d], true);
            }
        }
    }
    // combine partials in the old tree order: (p0+p1)+(p2+p3)
#pragma unroll
    for (int u = 0; u < 8; ++u) {
        accq[0][u] += accq[1][u];
        accq[2][u] += accq[3][u];
        accq[0][u] += accq[2][u];
    }
    const float inv = (deg > 0) ? 1.0f / (float)deg : 0.0f;
    unsigned short o[16];
#pragma unroll
    for (int u = 0; u < 8; ++u) {
        o[2 * u + 0] = f2bf(accq[0][u][0] * inv);
        o[2 * u + 1] = f2bf(accq[0][u][1] * inv);
    }
    unsigned short* mp = mean + (size_t)w * C + l * 16;  // 16 channels per lane
    *(uint4*)(mp + 0) = ((const uint4*)o)[0];
    *(uint4*)(mp + 8) = ((const uint4*)o)[1];
}

// ================= MFMA SAGE GEMM: relu([mean|h] @ [Wn;Ws] + b) =================
// Self (h) half stays bf16 — R15 PMC lesson: fp8 on the un-averaged self path
// quadruples absmax (0.031->0.117, fails). fp8 only where a mean follows.
// !FUSE_FC: outputs staged through LDS and stored as full coalesced lines
// (direct per-lane 1-2B stores caused 2.5x HBM write amplification — R13 PMC).
// Poison-robust by construction: control flow depends only on N and blockIdx.
template <int KT, bool FUSE_FC>
__global__ __launch_bounds__(256) void sage_gemm_mfma(const unsigned short* __restrict__ meanb,
                                                      const unsigned short* __restrict__ hb,
                                                      const unsigned short* __restrict__ Bpack,
                                                      const float* __restrict__ bias,
                                                      const float* __restrict__ fcw,
                                                      const float* __restrict__ fcb,
                                                      unsigned short* __restrict__ outb,
                                                      unsigned char* __restrict__ out8,
                                                      float* __restrict__ outf, int N) {
    constexpr int KH = KT / 2;
    constexpr int LDA = KT + 8;
    __shared__ unsigned short As[64 * LDA];
    const int t = threadIdx.x;
    const int row0 = blockIdx.x * 64;

    constexpr int SEGS = KT / 8;
    for (int c = t; c < 64 * SEGS; c += 256) {
        int r = c / SEGS, seg = c % SEGS;
        int rsrc = row0 + r;
        if (rsrc >= N) rsrc = N - 1;
        const unsigned short* srcp = (seg < SEGS / 2)
                                         ? meanb + (size_t)rsrc * KH + seg * 8
                                         : hb + (size_t)rsrc * KH + (seg - SEGS / 2) * 8;
        *(uint4*)&As[r * LDA + seg * 8] = *(const uint4*)srcp;
    }
    __syncthreads();

    const int lane = t & 63;
    const int wave = t >> 6;
    const int quad = lane >> 4;
    const int lo = lane & 15;

    floatx4 acc[8];
#pragma unroll
    for (int i = 0; i < 8; ++i)
#pragma unroll
        for (int r = 0; r < 4; ++r) acc[i][r] = 0.0f;

    const unsigned short* abase = &As[(wave * 16 + lo) * LDA + quad * 8];
#pragma unroll
    for (int s = 0; s < KT / 32; ++s) {
        short8 a = *(const short8*)(abase + s * 32);
        const short8* bp = (const short8*)Bpack + (size_t)(s * 8) * 64 + lane;
#pragma unroll
        for (int tt = 0; tt < 8; ++tt) {
            short8 b = bp[tt * 64];
            acc[tt] = __builtin_amdgcn_mfma_f32_16x16x32_bf16(a, b, acc[tt], 0, 0, 0);
        }
    }

    if (!FUSE_FC) {
        // ---- phase A: stage bf16 rows in LDS, stream out full 256B lines ----
        __syncthreads();  // all As (A-tile) reads complete before reuse
#pragma unroll
        for (int tt = 0; tt < 8; ++tt) {
            int col = tt * 16 + lo;
            float bv = bias[col];
#pragma unroll
            for (int r = 0; r < 4; ++r) {
                int rl = wave * 16 + quad * 4 + r;
                As[rl * LDA + col] = f2bf(fmaxf(acc[tt][r] + bv, 0.0f));
            }
        }
        __syncthreads();
        for (int i = t; i < 64 * (HID / 8); i += 256) {  // 16 threads/row, uint4 each
            int r = i >> 4, ch = i & 15;
            int row = row0 + r;
            if (row < N)
                *(uint4*)(outb + (size_t)row * HID + ch * 8) = *(const uint4*)&As[r * LDA + ch * 8];
        }
        // ---- phase B: recompute from live acc, stage fp8 rows, stream 128B lines ----
        __syncthreads();
        unsigned char* As8 = (unsigned char*)As;
#pragma unroll
        for (int tt = 0; tt < 8; ++tt) {
            int col = tt * 16 + lo;
            float bv = bias[col];
#pragma unroll
            for (int r = 0; r < 4; ++r) {
                int rl = wave * 16 + quad * 4 + r;
                float v = fmaxf(acc[tt][r] + bv, 0.0f);
                int p8 = __builtin_amdgcn_cvt_pk_fp8_f32(v, v, 0, false);
                As8[rl * (LDA * 2) + col] = (unsigned char)(p8 & 0xff);
            }
        }
        __syncthreads();
        for (int i = t; i < 64 * (HID / 16); i += 256) {  // 8 threads/row, uint4 each
            int r = i >> 3, ch = i & 7;
            int row = row0 + r;
            if (row < N)
                *(uint4*)(out8 + (size_t)row * HID + ch * 16) =
                    *(const uint4*)&As8[r * (LDA * 2) + ch * 16];
        }
    } else {
        float o0[4] = {}, o1[4] = {};
#pragma unroll
        for (int tt = 0; tt < 8; ++tt) {
            int col = tt * 16 + lo;
            float bv = bias[col];
            float w0 = fcw[col * 2 + 0];
            float w1 = fcw[col * 2 + 1];
#pragma unroll
            for (int r = 0; r < 4; ++r) {
                float v = fmaxf(acc[tt][r] + bv, 0.0f);
                o0[r] += v * w0;
                o1[r] += v * w1;
            }
        }
#pragma unroll
        for (int r = 0; r < 4; ++r) {
#pragma unroll
            for (int m = 8; m >= 1; m >>= 1) {
                o0[r] += __shfl_xor(o0[r], m, 16);
                o1[r] += __shfl_xor(o1[r], m, 16);
            }
        }
        if (lo == 0) {
#pragma unroll
            for (int r = 0; r < 4; ++r) {
                int row = row0 + wave * 16 + quad * 4 + r;
                if (row < N) {
                    outf[(size_t)row * 2 + 0] = o0[r] + fcb[0];
                    outf[(size_t)row * 2 + 1] = o1[r] + fcb[1];
                }
            }
        }
    }
}

extern "C" void kernel_launch(void* const* d_in, const int* in_sizes, int n_in,
                              void* d_out, int out_size, void* d_ws, size_t ws_size,
                              hipStream_t stream) {
    const float* x   = (const float*)d_in[0];
    const int*   ei  = (const int*)d_in[1];
    const float* Wn0 = (const float*)d_in[2];
    const float* Ws0 = (const float*)d_in[3];
    const float* b0  = (const float*)d_in[4];
    const float* Wn1 = (const float*)d_in[5];
    const float* Ws1 = (const float*)d_in[6];
    const float* b1  = (const float*)d_in[7];
    const float* fcw = (const float*)d_in[8];
    const float* fcb = (const float*)d_in[9];
    float* out = (float*)d_out;

    const int E = in_sizes[1] / 2;
    const int* src = ei;
    const int* dst = ei + E;
    const int N = N_NODES;
    const int chunk = (((E + NCB - 1) / NCB) + 3) & ~3;  // multiple of 4 for int4 paths

    // workspace layout
    char* ws = (char*)d_ws;
    size_t off = 0;
    int* table  = (int*)(ws + off); off += (size_t)NBUCK * NCB * 4;
    int* tot    = (int*)(ws + off); off += 4096;
    int* bstart = (int*)(ws + off); off += 4096;
    int* scan_done = (int*)(ws + off); off += 256;
    int* ptr    = (int*)(ws + off); off += (size_t)(N + 1) * 4 + 60; off &= ~(size_t)63;
    unsigned* binned = (unsigned*)(ws + off); off += (size_t)E * 4;
    int* sorted = (int*)(ws + off); off += (size_t)E * 4;
    off = (off + 255) & ~(size_t)255;
    unsigned short* x_bf   = (unsigned short*)(ws + off); off += (size_t)N * IN_CH * 2;
    unsigned short* mean0  = (unsigned short*)(ws + off); off += (size_t)N * IN_CH * 2;
    unsigned short* h1_bf  = (unsigned short*)(ws + off); off += (size_t)N * HID * 2;
    unsigned short* mean1  = (unsigned short*)(ws + off); off += (size_t)N * HID * 2;
    unsigned char*  h1_f8  = (unsigned char*)(ws + off);  off += (size_t)N * HID;
    unsigned char*  x_f8   = (unsigned char*)(ws + off);  off += (size_t)N * IN_CH;
    off = (off + 255) & ~(size_t)255;
    unsigned short* Bpack0 = (unsigned short*)(ws + off); off += (size_t)(2 * IN_CH / 32) * 8 * 64 * 8 * 2;
    unsigned short* Bpack1 = (unsigned short*)(ws + off); off += (size_t)(2 * HID / 32) * 8 * 64 * 8 * 2;

    // ---- CSR build + prep ----
    {
        int n4 = N * IN_CH / 4;
        int nblk = NCB + 24 + (n4 + 255) / 256;
        histprep_kernel<<<nblk, 256, 0, stream>>>(dst, table, E, chunk, x, x_bf, x_f8,
                                                  Wn0, Ws0, Bpack0, Wn1, Ws1, Bpack1,
                                                  scan_done, n4);
    }
    scan12_kernel<<<NBUCK, 256, 0, stream>>>(table, tot, bstart, ptr, scan_done, E);
    bin_kernel<<<NCB, 256, 0, stream>>>(src, dst, table, bstart, binned, E, chunk);
    place_kernel<<<NBUCK, 256, 0, stream>>>(binned, bstart, ptr, sorted, N, E);

    // ---- layer 0 (fp8 aggregation, bf16 self): 64 nodes/block (R=4) ----
    gather_mean_w16p<IN_CH><<<(N + 63) / 64, 256, 0, stream>>>(ptr, sorted, x_f8, mean0, N, E);
    sage_gemm_mfma<2 * IN_CH, false><<<(N + 63) / 64, 256, 0, stream>>>(
        mean0, x_bf, Bpack0, b0, nullptr, nullptr, h1_bf, h1_f8, nullptr, N);

    // ---- layer 1 (fp8 aggregation, bf16 self) + fused fc: 32 nodes/block (R=8) ----
    gather_mean_w16p<HID><<<(N + 31) / 32, 256, 0, stream>>>(ptr, sorted, h1_f8, mean1, N, E);
    sage_gemm_mfma<2 * HID, true><<<(N + 63) / 64, 256, 0, stream>>>(
        mean1, h1_bf, Bpack1, b1, fcw, fcb, nullptr, nullptr, out, N);
}